// Round 1
// baseline (1011.853 us; speedup 1.0000x reference)
//
#include <hip/hip_runtime.h>

// Aggregation: out[e] = segment_sum(M, dest)[src[e]] - M[rev_index[e]]
// E = 800,000 edges, D = 64 (fp32), N_NODES = 50,000.
// d_ws holds M_v accumulator: 50,000 * 64 * 4 B = 12.8 MB (fits in L2 aggregate).

#define D 64
#define N_NODES 50000

// Scatter-add: 16 threads per edge, each thread handles one float4 (4 scalar atomics).
__global__ void agg_scatter(const float* __restrict__ M,
                            const int* __restrict__ dest,
                            float* __restrict__ Mv,
                            int E) {
    int gid = blockIdx.x * blockDim.x + threadIdx.x;
    int e  = gid >> 4;   // 16 float4-slots per 64-float row
    int c4 = gid & 15;
    if (e >= E) return;
    int d = dest[e];
    float4 v = reinterpret_cast<const float4*>(M + (size_t)e * D)[c4];
    float* base = Mv + (size_t)d * D + c4 * 4;
    atomicAdd(base + 0, v.x);
    atomicAdd(base + 1, v.y);
    atomicAdd(base + 2, v.z);
    atomicAdd(base + 3, v.w);
}

// Gather: out[e] = Mv[src[e]] - M[rev[e]], 16 threads/edge, float4 each.
__global__ void agg_gather(const float* __restrict__ Mv,
                           const float* __restrict__ M,
                           const int* __restrict__ src,
                           const int* __restrict__ rev,
                           float* __restrict__ out,
                           int E) {
    int gid = blockIdx.x * blockDim.x + threadIdx.x;
    int e  = gid >> 4;
    int c4 = gid & 15;
    if (e >= E) return;
    int s = src[e];
    int r = rev[e];
    float4 a = reinterpret_cast<const float4*>(Mv + (size_t)s * D)[c4];
    float4 b = reinterpret_cast<const float4*>(M  + (size_t)r * D)[c4];
    float4 o;
    o.x = a.x - b.x;
    o.y = a.y - b.y;
    o.z = a.z - b.z;
    o.w = a.w - b.w;
    reinterpret_cast<float4*>(out + (size_t)e * D)[c4] = o;
}

extern "C" void kernel_launch(void* const* d_in, const int* in_sizes, int n_in,
                              void* d_out, int out_size, void* d_ws, size_t ws_size,
                              hipStream_t stream) {
    const float* M   = (const float*)d_in[0];
    const int*   ei  = (const int*)d_in[1];   // (2, E) row-major: [src | dest]
    const int*   rev = (const int*)d_in[2];
    // d_in[3] = dim_size (device scalar) — fixed-shape problem, hardcoded N_NODES.

    int E = in_sizes[0] / D;                  // 800,000
    const int* src  = ei;
    const int* dest = ei + E;

    float* Mv = (float*)d_ws;                 // 12.8 MB accumulator
    hipMemsetAsync(Mv, 0, (size_t)N_NODES * D * sizeof(float), stream);

    int threads = E * 16;                     // 16 lanes per edge
    int blocks  = (threads + 255) / 256;
    agg_scatter<<<blocks, 256, 0, stream>>>(M, dest, Mv, E);
    agg_gather<<<blocks, 256, 0, stream>>>(Mv, M, src, rev, (float*)d_out, E);
}

// Round 2
// 586.301 us; speedup vs baseline: 1.7258x; 1.7258x over previous
//
#include <hip/hip_runtime.h>

// out[e] = segment_sum(M, dest)[src[e]] - M[rev_index[e]]
// E = 800,000, D = 64 (fp32), N_NODES = 50,000.
// Strategy: build CSR by counting sort (int atomics only), then one-wave-per-node
// segmented reduction (no float atomics), then gather-subtract.

#define D 64
#define N_NODES 50000
#define SCAN_THREADS 1024

// K1: histogram of dest
__global__ void agg_hist(const int* __restrict__ dest, int* __restrict__ counts, int E) {
    int e = blockIdx.x * blockDim.x + threadIdx.x;
    if (e < E) atomicAdd(counts + dest[e], 1);
}

// K2: single-block exclusive scan of counts[N_NODES] in place; data[N_NODES] = total.
__global__ void agg_scan(int* __restrict__ data) {
    __shared__ int sums[SCAN_THREADS];
    const int N = N_NODES;
    int t = threadIdx.x;
    const int chunk = (N + SCAN_THREADS - 1) / SCAN_THREADS;  // 49
    int start = t * chunk;
    int end   = min(start + chunk, N);
    int s = 0;
    for (int i = start; i < end; ++i) s += data[i];
    sums[t] = s;
    __syncthreads();
    // Hillis-Steele inclusive scan over per-thread sums
    for (int off = 1; off < SCAN_THREADS; off <<= 1) {
        int v = sums[t];
        int u = (t >= off) ? sums[t - off] : 0;
        __syncthreads();
        sums[t] = v + u;
        __syncthreads();
    }
    int run = (t == 0) ? 0 : sums[t - 1];   // exclusive prefix for this chunk
    for (int i = start; i < end; ++i) {
        int c = data[i];
        data[i] = run;
        run += c;
    }
    if (t == SCAN_THREADS - 1) data[N] = run;  // == E
}

// K3: bin edge ids by dest using cursor (copy of offsets)
__global__ void agg_bin(const int* __restrict__ dest, int* __restrict__ cursor,
                        int* __restrict__ order, int E) {
    int e = blockIdx.x * blockDim.x + threadIdx.x;
    if (e < E) {
        int pos = atomicAdd(cursor + dest[e], 1);
        order[pos] = e;
    }
}

// K4: one wave per node; lane = feature dim. Coalesced 256 B row reads.
__global__ void agg_reduce(const float* __restrict__ M,
                           const int* __restrict__ order,
                           const int* __restrict__ offsets,
                           float* __restrict__ Mv) {
    int lane = threadIdx.x & 63;
    int node = (blockIdx.x * blockDim.x + threadIdx.x) >> 6;
    if (node >= N_NODES) return;
    int beg = offsets[node];
    int end = offsets[node + 1];
    float acc = 0.f;
    int i = beg;
    for (; i + 4 <= end; i += 4) {
        int e0 = order[i];
        int e1 = order[i + 1];
        int e2 = order[i + 2];
        int e3 = order[i + 3];
        float a0 = M[(size_t)e0 * D + lane];
        float a1 = M[(size_t)e1 * D + lane];
        float a2 = M[(size_t)e2 * D + lane];
        float a3 = M[(size_t)e3 * D + lane];
        acc += (a0 + a1) + (a2 + a3);
    }
    for (; i < end; ++i) acc += M[(size_t)order[i] * D + lane];
    Mv[(size_t)node * D + lane] = acc;
}

// K5: out[e] = Mv[src[e]] - M[rev[e]], 16 threads/edge, float4 each.
__global__ void agg_gather(const float* __restrict__ Mv,
                           const float* __restrict__ M,
                           const int* __restrict__ src,
                           const int* __restrict__ rev,
                           float* __restrict__ out,
                           int E) {
    int gid = blockIdx.x * blockDim.x + threadIdx.x;
    int e  = gid >> 4;
    int c4 = gid & 15;
    if (e >= E) return;
    int s = src[e];
    int r = rev[e];
    float4 a = reinterpret_cast<const float4*>(Mv + (size_t)s * D)[c4];
    float4 b = reinterpret_cast<const float4*>(M  + (size_t)r * D)[c4];
    float4 o;
    o.x = a.x - b.x;
    o.y = a.y - b.y;
    o.z = a.z - b.z;
    o.w = a.w - b.w;
    reinterpret_cast<float4*>(out + (size_t)e * D)[c4] = o;
}

extern "C" void kernel_launch(void* const* d_in, const int* in_sizes, int n_in,
                              void* d_out, int out_size, void* d_ws, size_t ws_size,
                              hipStream_t stream) {
    const float* M   = (const float*)d_in[0];
    const int*   ei  = (const int*)d_in[1];   // (2, E) row-major: [src | dest]
    const int*   rev = (const int*)d_in[2];

    int E = in_sizes[0] / D;                  // 800,000
    const int* src  = ei;
    const int* dest = ei + E;

    // Workspace layout (ints/floats, 256B-aligned chunks)
    int*   offsets = (int*)d_ws;                       // 50,001 ints (counts -> scan in place)
    int*   cursor  = offsets + 50304;                  // 50,001 ints
    int*   order   = cursor + 50304;                   // 800,000 ints
    float* Mv      = (float*)(order + 800128);         // 50,000*64 floats = 12.8 MB

    // counts = 0
    hipMemsetAsync(offsets, 0, (N_NODES + 1) * sizeof(int), stream);

    int eb = (E + 255) / 256;
    agg_hist<<<eb, 256, 0, stream>>>(dest, offsets, E);
    agg_scan<<<1, SCAN_THREADS, 0, stream>>>(offsets);
    hipMemcpyAsync(cursor, offsets, (N_NODES + 1) * sizeof(int),
                   hipMemcpyDeviceToDevice, stream);
    agg_bin<<<eb, 256, 0, stream>>>(dest, cursor, order, E);

    int rb = (N_NODES * 64 + 255) / 256;      // one wave per node
    agg_reduce<<<rb, 256, 0, stream>>>(M, order, offsets, Mv);

    int gb = (E * 16 + 255) / 256;
    agg_gather<<<gb, 256, 0, stream>>>(Mv, M, src, rev, (float*)d_out, E);
}